// Round 8
// baseline (448.825 us; speedup 1.0000x reference)
//
#include <hip/hip_runtime.h>

typedef short v8s __attribute__((ext_vector_type(8)));
typedef float v4f __attribute__((ext_vector_type(4)));
typedef float v32f __attribute__((ext_vector_type(32)));

__device__ __forceinline__ unsigned short f2bf(float f){
  unsigned u = __builtin_bit_cast(unsigned, f);
  return (unsigned short)((u + 0x7fffu + ((u>>16)&1u)) >> 16);
}
__device__ __forceinline__ float bf2f(unsigned short s){
  return __builtin_bit_cast(float, ((unsigned)s) << 16);
}

// -------- conv1x1 as MFMA GEMM, both tensors in one launch.
// Q/K out-channels (0..191) -> Sqk (in d_out); V out-channels (192..383) -> Sv (in ws).
// grid 4096 (2 tensors x 2048 n-tiles of 64), block 512 (8 waves, m-stripes of 48).
__global__ __launch_bounds__(512) void k_conv1x1(
    const float* __restrict__ hsi, const float* __restrict__ lidar,
    const unsigned short* __restrict__ Wfrag, const float* __restrict__ hqb,
    const float* __restrict__ lkb, unsigned short* __restrict__ Sqk,
    unsigned short* __restrict__ Sv)
{
  const int bx   = blockIdx.x;
  const int tens = bx >> 11;
  const int nt   = bx & 2047;
  const int b    = nt >> 8;
  const int hw0  = (nt & 255) << 6;
  const float* X = (tens ? lidar : hsi) + ((size_t)b * 192) * 16384 + hw0;
  const float* bias = tens ? lkb : hqb;

  __shared__ unsigned short Xt[64][200];   // transposed bf16 X tile, padded

  {
    const int c4   = (threadIdx.x & 15) * 4;
    const int krow = threadIdx.x >> 4;     // 0..31
    const float* xb2 = X + c4;
    float4 f[6];
    #pragma unroll
    for (int j = 0; j < 3; ++j){
      const int k = krow*2 + j*64;
      f[2*j]   = *(const float4*)(xb2 + (size_t)k * 16384);
      f[2*j+1] = *(const float4*)(xb2 + (size_t)(k+1) * 16384);
    }
    #pragma unroll
    for (int j = 0; j < 3; ++j){
      const int k = krow*2 + j*64;
      #pragma unroll
      for (int i2 = 0; i2 < 4; ++i2){
        const unsigned lo = f2bf(((const float*)&f[2*j])[i2]);
        const unsigned hi = f2bf(((const float*)&f[2*j+1])[i2]);
        *(unsigned*)&Xt[c4 + i2][k] = lo | (hi << 16);
      }
    }
  }
  __syncthreads();

  const int lane = threadIdx.x & 63;
  const int wid  = threadIdx.x >> 6;      // 0..7
  const int l15  = lane & 15;
  const int g    = lane >> 4;
  const int mstripe = wid * 48;
  const unsigned short* wb = Wfrag + ((size_t)(tens*8 + wid) * 18) * 512 + (lane << 3);

  v4f acc[3][4];
  #pragma unroll
  for (int i=0;i<3;i++)
    #pragma unroll
    for (int j=0;j<4;j++)
      acc[i][j] = (v4f){0.f,0.f,0.f,0.f};

  #pragma unroll
  for (int ks=0; ks<6; ++ks){
    const int k0 = ks*32;
    v8s af[3];
    #pragma unroll
    for (int mi=0; mi<3; ++mi)
      af[mi] = *(const v8s*)(wb + (size_t)(ks*3 + mi) * 512);
    #pragma unroll
    for (int ni=0; ni<4; ++ni){
      const v8s bfr = *(const v8s*)&Xt[ni*16 + l15][k0 + 8*g];
      #pragma unroll
      for (int mi=0; mi<3; ++mi)
        acc[mi][ni] = __builtin_amdgcn_mfma_f32_16x16x32_bf16(af[mi], bfr, acc[mi][ni], 0, 0, 0);
    }
  }

  unsigned short* outp;
  int cb;
  if (mstripe < 192){
    outp = Sqk + ((size_t)(tens*8 + b) * 192) * 16384 + hw0;
    cb = mstripe;
  } else {
    outp = Sv + ((size_t)(tens*8 + b) * 192) * 16384 + hw0;
    cb = mstripe - 192;
  }
  #pragma unroll
  for (int mi=0; mi<3; ++mi){
    #pragma unroll
    for (int r=0; r<4; ++r){
      const int co = mi*16 + 4*g + r;
      const float bs = bias[mstripe + co];
      #pragma unroll
      for (int ni=0; ni<4; ++ni)
        outp[(size_t)(cb + co)*16384 + ni*16 + l15] = f2bf(acc[mi][ni][r] + bs);
    }
  }
}

// -------- depthwise 3x3 SAME, V channels only (weights 192..383). Sv -> Vb.
// grid 24576, block 256. pc = (tens*8+b)*192 + c, c in [0,192)
__global__ __launch_bounds__(256) void k_dwv(
    const unsigned short* __restrict__ Sv, const float* __restrict__ hdw,
    const float* __restrict__ ldw, const float* __restrict__ hdb,
    const float* __restrict__ ldb, unsigned short* __restrict__ Vb)
{
  const int idx = blockIdx.x*256 + threadIdx.x;
  const int w8 = idx & 15;
  const int h  = (idx >> 4) & 127;
  const int pc = idx >> 11;            // 0..3071
  const int tens = (pc >= 1536);
  const int c  = pc % 192;
  const unsigned short* in = Sv + (size_t)pc*16384;

  float r[3][10];
  #pragma unroll
  for (int dy=0; dy<3; ++dy){
    const int hh = h + dy - 1;
    if (hh >= 0 && hh < 128){
      const unsigned short* row = in + hh*128 + w8*8;
      const v8s m = *(const v8s*)row;
      #pragma unroll
      for (int i=0;i<8;++i) r[dy][i+1] = bf2f((unsigned short)m[i]);
      r[dy][0] = (w8 > 0)  ? bf2f(row[-1]) : 0.f;
      r[dy][9] = (w8 < 15) ? bf2f(row[8])  : 0.f;
    } else {
      #pragma unroll
      for (int i=0;i<10;++i) r[dy][i] = 0.f;
    }
  }
  const float* wp = (tens ? ldw : hdw) + (192 + c)*9;
  const float k00=wp[0],k01=wp[1],k02=wp[2],k10=wp[3],k11=wp[4],k12=wp[5],k20=wp[6],k21=wp[7],k22=wp[8];
  const float bs = (tens ? ldb : hdb)[192 + c];
  v8s out;
  #pragma unroll
  for (int j=0;j<8;++j){
    float a = bs
      + r[0][j]*k00 + r[0][j+1]*k01 + r[0][j+2]*k02
      + r[1][j]*k10 + r[1][j+1]*k11 + r[1][j+2]*k12
      + r[2][j]*k20 + r[2][j+1]*k21 + r[2][j+2]*k22;
    out[j] = (short)f2bf(a);
  }
  *(v8s*)(Vb + (size_t)pc*16384 + h*128 + w8*8) = out;
}

// -------- fused dw(Q/K) + QK^T partials + row sumsq via Gram MFMAs.
// grid (48, 16), block 256 (4 waves, 256 s each). P: [48][64][1088]
__global__ __launch_bounds__(256) void k_qkdw(
    const unsigned short* __restrict__ Sqk, const float* __restrict__ hdw,
    const float* __restrict__ ldw, const float* __restrict__ hdb,
    const float* __restrict__ ldb, float* __restrict__ P)
{
  const int bh = blockIdx.x, split = blockIdx.y;
  const int lane = threadIdx.x & 63, wid = threadIdx.x >> 6;
  const int l15 = lane & 15, g = lane >> 4;
  const int b = bh/6, hd = bh%6;
  const unsigned short* qpb = Sqk + ((size_t)(0*8 + b)*192 + hd*32)*16384;  // hsi q
  const unsigned short* kpb = Sqk + ((size_t)(1*8 + b)*192 + hd*32)*16384;  // lidar k
  const int s0 = (split*4 + wid)*256;

  // hoist dw weights: per lane, channels hd*32 + mi*16 + l15 for mi=0,1
  float wq[2][9], bq[2], wk[2][9], bk[2];
  #pragma unroll
  for (int mi=0; mi<2; ++mi){
    const int c = hd*32 + mi*16 + l15;
    #pragma unroll
    for (int j=0;j<9;++j){ wq[mi][j] = hdw[c*9+j]; wk[mi][j] = ldw[c*9+j]; }
    bq[mi] = hdb[c]; bk[mi] = ldb[c];
  }

  v4f aqk[2][2], aqq[2], akk[2];
  #pragma unroll
  for (int i=0;i<2;i++){
    aqq[i] = (v4f){0.f,0.f,0.f,0.f};
    akk[i] = (v4f){0.f,0.f,0.f,0.f};
    #pragma unroll
    for (int j=0;j<2;j++) aqk[i][j] = (v4f){0.f,0.f,0.f,0.f};
  }

  #pragma unroll
  for (int ks=0; ks<8; ++ks){
    const int s = s0 + ks*32 + 8*g;
    const int h = s >> 7;
    const int w0 = s & 127;
    v8s qf[2], kf[2];
    #pragma unroll
    for (int mi=0; mi<2; ++mi){
      #pragma unroll
      for (int qk=0; qk<2; ++qk){
        const unsigned short* plane = (qk ? kpb : qpb) + (size_t)(mi*16 + l15)*16384;
        const float* w9 = qk ? wk[mi] : wq[mi];
        const float bs = qk ? bk[mi] : bq[mi];
        float a9[3][10];
        #pragma unroll
        for (int dy=0; dy<3; ++dy){
          const int hh = h + dy - 1;
          if (hh >= 0 && hh < 128){
            const unsigned short* rp = plane + hh*128;
            const v8s m = *(const v8s*)(rp + w0);
            #pragma unroll
            for (int j=0;j<8;++j) a9[dy][j+1] = bf2f((unsigned short)m[j]);
            a9[dy][0] = (w0 > 0)   ? bf2f(rp[w0-1]) : 0.f;
            a9[dy][9] = (w0 < 120) ? bf2f(rp[w0+8]) : 0.f;
          } else {
            #pragma unroll
            for (int j=0;j<10;++j) a9[dy][j] = 0.f;
          }
        }
        v8s o;
        #pragma unroll
        for (int j=0;j<8;++j){
          float a = bs
            + a9[0][j]*w9[0] + a9[0][j+1]*w9[1] + a9[0][j+2]*w9[2]
            + a9[1][j]*w9[3] + a9[1][j+1]*w9[4] + a9[1][j+2]*w9[5]
            + a9[2][j]*w9[6] + a9[2][j+1]*w9[7] + a9[2][j+2]*w9[8];
          o[j] = (short)f2bf(a);
        }
        if (qk) kf[mi] = o; else qf[mi] = o;
      }
    }
    #pragma unroll
    for (int mi=0;mi<2;++mi)
      #pragma unroll
      for (int ni=0;ni<2;++ni)
        aqk[mi][ni] = __builtin_amdgcn_mfma_f32_16x16x32_bf16(qf[mi], kf[ni], aqk[mi][ni],0,0,0);
    #pragma unroll
    for (int mi=0;mi<2;++mi){
      aqq[mi] = __builtin_amdgcn_mfma_f32_16x16x32_bf16(qf[mi], qf[mi], aqq[mi],0,0,0);
      akk[mi] = __builtin_amdgcn_mfma_f32_16x16x32_bf16(kf[mi], kf[mi], akk[mi],0,0,0);
    }
  }
  float* slot = P + ((size_t)bh*64 + split*4 + wid)*1088;
  #pragma unroll
  for (int mi=0;mi<2;++mi)
    #pragma unroll
    for (int ni=0;ni<2;++ni)
      #pragma unroll
      for (int r=0;r<4;++r)
        slot[(mi*16 + 4*g + r)*32 + ni*16 + l15] = aqk[mi][ni][r];
  #pragma unroll
  for (int mi=0;mi<2;++mi)
    #pragma unroll
    for (int r=0;r<4;++r)
      if (l15 == 4*g + r){
        slot[1024 + mi*16 + l15] = aqq[mi][r];
        slot[1056 + mi*16 + l15] = akk[mi][r];
      }
}

// -------- reduce partials, l2-normalize, temperature, softmax, fold +I -> A[48][32][32]
__global__ __launch_bounds__(256) void k_sm(
    const float* __restrict__ P, const float* __restrict__ temp, float* __restrict__ A)
{
  __shared__ float red[1088];
  const int bh = blockIdx.x, t = threadIdx.x;
  const float* base = P + (size_t)bh*64*1088;
  for (int i=t; i<1088; i+=256){
    float s = 0.f;
    for (int sl=0; sl<64; ++sl) s += base[(size_t)sl*1088 + i];
    red[i] = s;
  }
  __syncthreads();
  const int c = t >> 3, dq = t & 7;
  const float qn = fmaxf(sqrtf(red[1024+c]), 1e-12f);
  const float tp = temp[bh % 6];
  float v[4];
  #pragma unroll
  for (int r=0;r<4;++r){
    const int d = dq*4 + r;
    const float kn = fmaxf(sqrtf(red[1056+d]), 1e-12f);
    v[r] = red[c*32+d] / (qn*kn) * tp;
  }
  float mx = fmaxf(fmaxf(v[0],v[1]), fmaxf(v[2],v[3]));
  mx = fmaxf(mx, __shfl_xor(mx,1));
  mx = fmaxf(mx, __shfl_xor(mx,2));
  mx = fmaxf(mx, __shfl_xor(mx,4));
  float e[4]; float sum = 0.f;
  #pragma unroll
  for (int r=0;r<4;++r){ e[r] = __expf(v[r]-mx); sum += e[r]; }
  sum += __shfl_xor(sum,1); sum += __shfl_xor(sum,2); sum += __shfl_xor(sum,4);
  const float inv = 1.f/sum;
  #pragma unroll
  for (int r=0;r<4;++r){
    const int d = dq*4 + r;
    A[(size_t)bh*1024 + c*32 + d] = e[r]*inv + ((c == d) ? 1.f : 0.f);
  }
}

#define R32(M) M(0) M(1) M(2) M(3) M(4) M(5) M(6) M(7) M(8) M(9) M(10) M(11) M(12) M(13) M(14) M(15) \
               M(16) M(17) M(18) M(19) M(20) M(21) M(22) M(23) M(24) M(25) M(26) M(27) M(28) M(29) M(30) M(31)

// -------- out = (A+I)@V + x, one tensor per block. grid (96, 32), block 256, 2 cols/thread
__global__ __launch_bounds__(256) void k_out(
    const float* __restrict__ A, const unsigned short* __restrict__ Vb,
    const float* __restrict__ hsi, const float* __restrict__ lidar,
    float* __restrict__ outh, float* __restrict__ outl)
{
  const int tens = blockIdx.x & 1;
  const int bh = blockIdx.x >> 1;
  const int s = (blockIdx.y*256 + threadIdx.x)*2;
  const int b = bh/6, hd = bh%6;
  const float* Ab = A + (size_t)bh*1024;
  const unsigned short* V = Vb + ((size_t)(tens*8 + b)*192 + hd*32)*16384 + s;
  const float* X = (tens ? lidar : hsi) + ((size_t)b*192 + hd*32)*16384 + s;
  float* O = (tens ? outl : outh) + ((size_t)b*192 + hd*32)*16384 + s;

  v32f vx, vy;
#define LD_V(dd) { const unsigned u = *(const unsigned*)(V + (size_t)(dd)*16384); \
                   vx[dd] = bf2f((unsigned short)u); vy[dd] = bf2f((unsigned short)(u >> 16)); }
  R32(LD_V)
#undef LD_V

  for (int c=0; c<32; ++c){
    const float* Arow = Ab + c*32;
    const float2 x = *(const float2*)(X + (size_t)c*16384);
    float ax = x.x, ay = x.y;
#define FMA_D(dd) { const float a = Arow[dd]; ax += a*vx[dd]; ay += a*vy[dd]; }
    R32(FMA_D)
#undef FMA_D
    float2 o; o.x = ax; o.y = ay;
    *(float2*)(O + (size_t)c*16384) = o;
  }
}

// -------- convert both 1x1 weights to bf16 in MFMA fragment order:
// Wfrag[tens][wid(8)][ks(6)][mi(3)][lane(64)][8]
__global__ __launch_bounds__(256) void k_wcvt(
    const float* __restrict__ a, const float* __restrict__ b, unsigned short* __restrict__ o)
{
  const int i = blockIdx.x*256 + threadIdx.x;
  if (i >= 147456) return;
  const int jj = i & 7;
  const int l  = (i >> 3) & 63;
  const int rest = i >> 9;          // ((tens*8+wid)*6+ks)*3+mi, 0..287
  const int mi = rest % 3;
  const int ks = (rest / 3) % 6;
  const int q  = rest / 18;         // tens*8 + wid
  const int wid = q & 7, tens = q >> 3;
  const int row = wid*48 + mi*16 + (l & 15);
  const int col = ks*32 + (l >> 4)*8 + jj;
  const float* src = tens ? b : a;
  o[i] = f2bf(src[row*192 + col]);
}

extern "C" void kernel_launch(void* const* d_in, const int* in_sizes, int n_in,
                              void* d_out, int out_size, void* d_ws, size_t ws_size,
                              hipStream_t stream) {
  const float* hsi   = (const float*)d_in[0];
  const float* lidar = (const float*)d_in[1];
  const float* hqw   = (const float*)d_in[2];
  const float* hqb   = (const float*)d_in[3];
  const float* lkw   = (const float*)d_in[4];
  const float* lkb   = (const float*)d_in[5];
  const float* hdw   = (const float*)d_in[6];
  const float* hdb   = (const float*)d_in[7];
  const float* ldw   = (const float*)d_in[8];
  const float* ldb   = (const float*)d_in[9];
  const float* temp  = (const float*)d_in[10];

  char* ws = (char*)d_ws;
  unsigned short* Sv  = (unsigned short*)(ws);                 // 100663296 B (V half of conv out)
  unsigned short* Vb  = (unsigned short*)(ws + 100663296);     // 100663296 B (dw'd V, bf16)
  unsigned short* Wbf = (unsigned short*)(ws + 201326592);     // 294912 B
  float* P            = (float*)(ws + 201621504);              // 13369344 B
  float* A            = (float*)(ws + 214990848);              // 196608 B

  float* outh = (float*)d_out;
  float* outl = outh + 25165824;
  // Q/K half of conv output staged inside d_out (dead before k_out writes)
  unsigned short* Sqk = (unsigned short*)d_out;                // 100663296 B

  k_wcvt<<<576, 256, 0, stream>>>(hqw, lkw, Wbf);
  k_conv1x1<<<4096, 512, 0, stream>>>(hsi, lidar, Wbf, hqb, lkb, Sqk, Sv);
  k_dwv<<<24576, 256, 0, stream>>>(Sv, hdw, ldw, hdb, ldb, Vb);
  k_qkdw<<<dim3(48, 16), 256, 0, stream>>>(Sqk, hdw, ldw, hdb, ldb, P);
  k_sm<<<48, 256, 0, stream>>>(P, temp, A);
  k_out<<<dim3(96, 32), 256, 0, stream>>>(A, Vb, hsi, lidar, outh, outl);
}

// Round 9
// 336.445 us; speedup vs baseline: 1.3340x; 1.3340x over previous
//
#include <hip/hip_runtime.h>

typedef short v8s __attribute__((ext_vector_type(8)));
typedef float v4f __attribute__((ext_vector_type(4)));
typedef float v32f __attribute__((ext_vector_type(32)));

__device__ __forceinline__ unsigned short f2bf(float f){
  unsigned u = __builtin_bit_cast(unsigned, f);
  return (unsigned short)((u + 0x7fffu + ((u>>16)&1u)) >> 16);
}
__device__ __forceinline__ float bf2f(unsigned short s){
  return __builtin_bit_cast(float, ((unsigned)s) << 16);
}

// -------- conv1x1 as MFMA GEMM, both tensors in one launch.
// Q/K out-channels (0..191) -> Sqk (in d_out); V out-channels (192..383) -> Sv (in ws).
// grid 4096 (2 tensors x 2048 n-tiles of 64), block 512 (8 waves, m-stripes of 48).
__global__ __launch_bounds__(512) void k_conv1x1(
    const float* __restrict__ hsi, const float* __restrict__ lidar,
    const unsigned short* __restrict__ Wfrag, const float* __restrict__ hqb,
    const float* __restrict__ lkb, unsigned short* __restrict__ Sqk,
    unsigned short* __restrict__ Sv)
{
  const int bx   = blockIdx.x;
  const int tens = bx >> 11;
  const int nt   = bx & 2047;
  const int b    = nt >> 8;
  const int hw0  = (nt & 255) << 6;
  const float* X = (tens ? lidar : hsi) + ((size_t)b * 192) * 16384 + hw0;
  const float* bias = tens ? lkb : hqb;

  __shared__ unsigned short Xt[64][200];   // transposed bf16 X tile, padded

  {
    const int c4   = (threadIdx.x & 15) * 4;
    const int krow = threadIdx.x >> 4;     // 0..31
    const float* xb2 = X + c4;
    float4 f[6];
    #pragma unroll
    for (int j = 0; j < 3; ++j){
      const int k = krow*2 + j*64;
      f[2*j]   = *(const float4*)(xb2 + (size_t)k * 16384);
      f[2*j+1] = *(const float4*)(xb2 + (size_t)(k+1) * 16384);
    }
    #pragma unroll
    for (int j = 0; j < 3; ++j){
      const int k = krow*2 + j*64;
      #pragma unroll
      for (int i2 = 0; i2 < 4; ++i2){
        const unsigned lo = f2bf(((const float*)&f[2*j])[i2]);
        const unsigned hi = f2bf(((const float*)&f[2*j+1])[i2]);
        *(unsigned*)&Xt[c4 + i2][k] = lo | (hi << 16);
      }
    }
  }
  __syncthreads();

  const int lane = threadIdx.x & 63;
  const int wid  = threadIdx.x >> 6;      // 0..7
  const int l15  = lane & 15;
  const int g    = lane >> 4;
  const int mstripe = wid * 48;
  const unsigned short* wb = Wfrag + ((size_t)(tens*8 + wid) * 18) * 512 + (lane << 3);

  v4f acc[3][4];
  #pragma unroll
  for (int i=0;i<3;i++)
    #pragma unroll
    for (int j=0;j<4;j++)
      acc[i][j] = (v4f){0.f,0.f,0.f,0.f};

  #pragma unroll
  for (int ks=0; ks<6; ++ks){
    const int k0 = ks*32;
    v8s af[3];
    #pragma unroll
    for (int mi=0; mi<3; ++mi)
      af[mi] = *(const v8s*)(wb + (size_t)(ks*3 + mi) * 512);
    #pragma unroll
    for (int ni=0; ni<4; ++ni){
      const v8s bfr = *(const v8s*)&Xt[ni*16 + l15][k0 + 8*g];
      #pragma unroll
      for (int mi=0; mi<3; ++mi)
        acc[mi][ni] = __builtin_amdgcn_mfma_f32_16x16x32_bf16(af[mi], bfr, acc[mi][ni], 0, 0, 0);
    }
  }

  unsigned short* outp;
  int cb;
  if (mstripe < 192){
    outp = Sqk + ((size_t)(tens*8 + b) * 192) * 16384 + hw0;
    cb = mstripe;
  } else {
    outp = Sv + ((size_t)(tens*8 + b) * 192) * 16384 + hw0;
    cb = mstripe - 192;
  }
  #pragma unroll
  for (int mi=0; mi<3; ++mi){
    #pragma unroll
    for (int r=0; r<4; ++r){
      const int co = mi*16 + 4*g + r;
      const float bs = bias[mstripe + co];
      #pragma unroll
      for (int ni=0; ni<4; ++ni)
        outp[(size_t)(cb + co)*16384 + ni*16 + l15] = f2bf(acc[mi][ni][r] + bs);
    }
  }
}

// -------- depthwise 3x3 SAME, LDS-staged. All 6144 planes (Q/K then V) in one launch.
// block = 16-row x 128-w tile of one plane; stage 18 rows in LDS (row pad +8 shorts).
// grid 49152: bx>>3 = gp (0..6143), bx&7 = ytile. gp<3072: Sqk->QKd (woff 0); else Sv->Vb (woff 192).
__global__ __launch_bounds__(256) void k_dw2(
    const unsigned short* __restrict__ Sqk, const unsigned short* __restrict__ Sv,
    const float* __restrict__ hdw, const float* __restrict__ ldw,
    const float* __restrict__ hdb, const float* __restrict__ ldb,
    unsigned short* __restrict__ QKd, unsigned short* __restrict__ Vb)
{
  const int bx = blockIdx.x;
  const int ytile = bx & 7;
  const int gp = bx >> 3;               // 0..6143
  const int half = (gp >= 3072);        // 0: Q/K, 1: V
  const int p = half ? gp - 3072 : gp;  // plane in buffer, 0..3071
  const int tens = (p >= 1536);
  const int c = p % 192;
  const int woff = half ? 192 : 0;
  const unsigned short* in = (half ? Sv : Sqk) + (size_t)p*16384;
  unsigned short* out = (half ? Vb : QKd) + (size_t)p*16384;
  const int h0 = ytile*16;
  const int t = threadIdx.x;

  __shared__ __align__(16) unsigned short lds[18*136];  // 18 rows, stride 136 shorts

  // stage rows h0-1 .. h0+16 (zero outside), coalesced v8s
  #pragma unroll
  for (int it=0; it<2; ++it){
    const int slot = it*256 + t;
    if (slot < 288){
      const int row = slot >> 4;        // 0..17
      const int w16 = slot & 15;
      const int gr = h0 - 1 + row;
      v8s val = (v8s){0,0,0,0,0,0,0,0};
      if (gr >= 0 && gr < 128)
        val = *(const v8s*)(in + gr*128 + w16*8);
      *(v8s*)&lds[row*136 + w16*8] = val;
    }
  }
  __syncthreads();

  const int w8 = t & 15;
  const int hr = t >> 4;                // 0..15
  const int w0 = w8*8;

  float a9[3][10];
  #pragma unroll
  for (int dy=0; dy<3; ++dy){
    const unsigned short* rp = &lds[(hr + dy)*136];
    const v8s m = *(const v8s*)(rp + w0);
    #pragma unroll
    for (int j=0;j<8;++j) a9[dy][j+1] = bf2f((unsigned short)m[j]);
    a9[dy][0] = (w8 > 0)  ? bf2f(rp[w0-1]) : 0.f;
    a9[dy][9] = (w8 < 15) ? bf2f(rp[w0+8]) : 0.f;
  }

  const float* wp = (tens ? ldw : hdw) + (woff + c)*9;
  const float k00=wp[0],k01=wp[1],k02=wp[2],k10=wp[3],k11=wp[4],k12=wp[5],k20=wp[6],k21=wp[7],k22=wp[8];
  const float bs = (tens ? ldb : hdb)[woff + c];
  v8s o;
  #pragma unroll
  for (int j=0;j<8;++j){
    float a = bs
      + a9[0][j]*k00 + a9[0][j+1]*k01 + a9[0][j+2]*k02
      + a9[1][j]*k10 + a9[1][j+1]*k11 + a9[1][j+2]*k12
      + a9[2][j]*k20 + a9[2][j+1]*k21 + a9[2][j+2]*k22;
    o[j] = (short)f2bf(a);
  }
  *(v8s*)(out + (h0 + hr)*128 + w0) = o;
}

// -------- QK^T partials + row sumsq via Gram MFMAs.
// grid (48, 16), block 256 (4 waves, 256 s each). P: [48][64][1088]
__global__ __launch_bounds__(256) void k_qk(
    const unsigned short* __restrict__ QKd, float* __restrict__ P)
{
  const int bh = blockIdx.x, split = blockIdx.y;
  const int lane = threadIdx.x & 63, wid = threadIdx.x >> 6;
  const int l15 = lane & 15, g = lane >> 4;
  const int b = bh/6, hd = bh%6;
  const unsigned short* qb = QKd + ((size_t)(0*8 + b)*192 + hd*32)*16384;
  const unsigned short* kb = QKd + ((size_t)(1*8 + b)*192 + hd*32)*16384;
  const int s0 = (split*4 + wid)*256;

  v4f aqk[2][2], aqq[2], akk[2];
  #pragma unroll
  for (int i=0;i<2;i++){
    aqq[i] = (v4f){0.f,0.f,0.f,0.f};
    akk[i] = (v4f){0.f,0.f,0.f,0.f};
    #pragma unroll
    for (int j=0;j<2;j++) aqk[i][j] = (v4f){0.f,0.f,0.f,0.f};
  }

  #pragma unroll
  for (int ks=0; ks<8; ++ks){
    const int s = s0 + ks*32 + 8*g;
    v8s qf[2], kf[2];
    #pragma unroll
    for (int mi=0;mi<2;++mi) qf[mi] = *(const v8s*)(qb + (size_t)(mi*16 + l15)*16384 + s);
    #pragma unroll
    for (int ni=0;ni<2;++ni) kf[ni] = *(const v8s*)(kb + (size_t)(ni*16 + l15)*16384 + s);
    #pragma unroll
    for (int mi=0;mi<2;++mi)
      #pragma unroll
      for (int ni=0;ni<2;++ni)
        aqk[mi][ni] = __builtin_amdgcn_mfma_f32_16x16x32_bf16(qf[mi], kf[ni], aqk[mi][ni],0,0,0);
    #pragma unroll
    for (int mi=0;mi<2;++mi){
      aqq[mi] = __builtin_amdgcn_mfma_f32_16x16x32_bf16(qf[mi], qf[mi], aqq[mi],0,0,0);
      akk[mi] = __builtin_amdgcn_mfma_f32_16x16x32_bf16(kf[mi], kf[mi], akk[mi],0,0,0);
    }
  }
  float* slot = P + ((size_t)bh*64 + split*4 + wid)*1088;
  #pragma unroll
  for (int mi=0;mi<2;++mi)
    #pragma unroll
    for (int ni=0;ni<2;++ni)
      #pragma unroll
      for (int r=0;r<4;++r)
        slot[(mi*16 + 4*g + r)*32 + ni*16 + l15] = aqk[mi][ni][r];
  #pragma unroll
  for (int mi=0;mi<2;++mi)
    #pragma unroll
    for (int r=0;r<4;++r)
      if (l15 == 4*g + r){
        slot[1024 + mi*16 + l15] = aqq[mi][r];
        slot[1056 + mi*16 + l15] = akk[mi][r];
      }
}

// -------- reduce partials, l2-normalize, temperature, softmax, fold +I -> A[48][32][32]
__global__ __launch_bounds__(256) void k_sm(
    const float* __restrict__ P, const float* __restrict__ temp, float* __restrict__ A)
{
  __shared__ float red[1088];
  const int bh = blockIdx.x, t = threadIdx.x;
  const float* base = P + (size_t)bh*64*1088;
  for (int i=t; i<1088; i+=256){
    float s = 0.f;
    for (int sl=0; sl<64; ++sl) s += base[(size_t)sl*1088 + i];
    red[i] = s;
  }
  __syncthreads();
  const int c = t >> 3, dq = t & 7;
  const float qn = fmaxf(sqrtf(red[1024+c]), 1e-12f);
  const float tp = temp[bh % 6];
  float v[4];
  #pragma unroll
  for (int r=0;r<4;++r){
    const int d = dq*4 + r;
    const float kn = fmaxf(sqrtf(red[1056+d]), 1e-12f);
    v[r] = red[c*32+d] / (qn*kn) * tp;
  }
  float mx = fmaxf(fmaxf(v[0],v[1]), fmaxf(v[2],v[3]));
  mx = fmaxf(mx, __shfl_xor(mx,1));
  mx = fmaxf(mx, __shfl_xor(mx,2));
  mx = fmaxf(mx, __shfl_xor(mx,4));
  float e[4]; float sum = 0.f;
  #pragma unroll
  for (int r=0;r<4;++r){ e[r] = __expf(v[r]-mx); sum += e[r]; }
  sum += __shfl_xor(sum,1); sum += __shfl_xor(sum,2); sum += __shfl_xor(sum,4);
  const float inv = 1.f/sum;
  #pragma unroll
  for (int r=0;r<4;++r){
    const int d = dq*4 + r;
    A[(size_t)bh*1024 + c*32 + d] = e[r]*inv + ((c == d) ? 1.f : 0.f);
  }
}

#define R32(M) M(0) M(1) M(2) M(3) M(4) M(5) M(6) M(7) M(8) M(9) M(10) M(11) M(12) M(13) M(14) M(15) \
               M(16) M(17) M(18) M(19) M(20) M(21) M(22) M(23) M(24) M(25) M(26) M(27) M(28) M(29) M(30) M(31)

// -------- out = (A+I)@V + x, one tensor per block. grid (96, 32), block 256, 2 cols/thread
__global__ __launch_bounds__(256) void k_out(
    const float* __restrict__ A, const unsigned short* __restrict__ Vb,
    const float* __restrict__ hsi, const float* __restrict__ lidar,
    float* __restrict__ outh, float* __restrict__ outl)
{
  const int tens = blockIdx.x & 1;
  const int bh = blockIdx.x >> 1;
  const int s = (blockIdx.y*256 + threadIdx.x)*2;
  const int b = bh/6, hd = bh%6;
  const float* Ab = A + (size_t)bh*1024;
  const unsigned short* V = Vb + ((size_t)(tens*8 + b)*192 + hd*32)*16384 + s;
  const float* X = (tens ? lidar : hsi) + ((size_t)b*192 + hd*32)*16384 + s;
  float* O = (tens ? outl : outh) + ((size_t)b*192 + hd*32)*16384 + s;

  v32f vx, vy;
#define LD_V(dd) { const unsigned u = *(const unsigned*)(V + (size_t)(dd)*16384); \
                   vx[dd] = bf2f((unsigned short)u); vy[dd] = bf2f((unsigned short)(u >> 16)); }
  R32(LD_V)
#undef LD_V

  for (int c=0; c<32; ++c){
    const float* Arow = Ab + c*32;
    const float2 x = *(const float2*)(X + (size_t)c*16384);
    float ax = x.x, ay = x.y;
#define FMA_D(dd) { const float a = Arow[dd]; ax += a*vx[dd]; ay += a*vy[dd]; }
    R32(FMA_D)
#undef FMA_D
    float2 o; o.x = ax; o.y = ay;
    *(float2*)(O + (size_t)c*16384) = o;
  }
}

// -------- convert both 1x1 weights to bf16 in MFMA fragment order:
// Wfrag[tens][wid(8)][ks(6)][mi(3)][lane(64)][8]
__global__ __launch_bounds__(256) void k_wcvt(
    const float* __restrict__ a, const float* __restrict__ b, unsigned short* __restrict__ o)
{
  const int i = blockIdx.x*256 + threadIdx.x;
  if (i >= 147456) return;
  const int jj = i & 7;
  const int l  = (i >> 3) & 63;
  const int rest = i >> 9;          // ((tens*8+wid)*6+ks)*3+mi, 0..287
  const int mi = rest % 3;
  const int ks = (rest / 3) % 6;
  const int q  = rest / 18;         // tens*8 + wid
  const int wid = q & 7, tens = q >> 3;
  const int row = wid*48 + mi*16 + (l & 15);
  const int col = ks*32 + (l >> 4)*8 + jj;
  const float* src = tens ? b : a;
  o[i] = f2bf(src[row*192 + col]);
}

extern "C" void kernel_launch(void* const* d_in, const int* in_sizes, int n_in,
                              void* d_out, int out_size, void* d_ws, size_t ws_size,
                              hipStream_t stream) {
  const float* hsi   = (const float*)d_in[0];
  const float* lidar = (const float*)d_in[1];
  const float* hqw   = (const float*)d_in[2];
  const float* hqb   = (const float*)d_in[3];
  const float* lkw   = (const float*)d_in[4];
  const float* lkb   = (const float*)d_in[5];
  const float* hdw   = (const float*)d_in[6];
  const float* hdb   = (const float*)d_in[7];
  const float* ldw   = (const float*)d_in[8];
  const float* ldb   = (const float*)d_in[9];
  const float* temp  = (const float*)d_in[10];

  char* ws = (char*)d_ws;
  unsigned short* Sv  = (unsigned short*)(ws);                 // 100663296 B (V half of conv out)
  unsigned short* Vb  = (unsigned short*)(ws + 100663296);     // 100663296 B (dw'd V, bf16)
  unsigned short* Wbf = (unsigned short*)(ws + 201326592);     // 294912 B
  float* P            = (float*)(ws + 201621504);              // 13369344 B
  float* A            = (float*)(ws + 214990848);              // 196608 B

  float* outh = (float*)d_out;
  float* outl = outh + 25165824;
  // d_out staging: first half = Sqk (conv Q/K out), second half = QKd (dw'd Q/K).
  // Both dead before k_out writes (k_out reads only A, Vb, hsi, lidar).
  unsigned short* Sqk = (unsigned short*)d_out;                          // 100663296 B
  unsigned short* QKd = (unsigned short*)((char*)d_out + 100663296);     // 100663296 B

  k_wcvt<<<576, 256, 0, stream>>>(hqw, lkw, Wbf);
  k_conv1x1<<<4096, 512, 0, stream>>>(hsi, lidar, Wbf, hqb, lkb, Sqk, Sv);
  k_dw2<<<49152, 256, 0, stream>>>(Sqk, Sv, hdw, ldw, hdb, ldb, QKd, Vb);
  k_qk<<<dim3(48, 16), 256, 0, stream>>>(QKd, P);
  k_sm<<<48, 256, 0, stream>>>(P, temp, A);
  k_out<<<dim3(96, 32), 256, 0, stream>>>(A, Vb, hsi, lidar, outh, outl);
}